// Round 6
// baseline (164.546 us; speedup 1.0000x reference)
//
#include <hip/hip_runtime.h>
#include <stdint.h>

// Problem constants (fixed by reference setup_inputs):
//   qt:     (H=25920, S=64, D=64) f32
//   k:      (H, 1, D) f32          -- DEAD: softmax over singleton axis == 1
//   scaleb: (H, 1, 1) f32          -- DEAD: same reason
//   biasb:  (H, 1, 1) f32          -- zeros in setup; a5 = mask * biasb/keep
// out = qt + broadcast(a5) ; a5[h,s] = (bernoulli_keep ? 1/keep : 0) * biasb[h]
//
// Memory-bound: ~850 MB traffic -> ~135 us roofline @ 6.3 TB/s copy ceiling.
// R0: per-element biasb load + branch -> 175 us (4.85 TB/s).
// R1: serial scan kernel + global flag -> 202 us (regression).
// R2: per-head slab copy, wave-uniform biasb -> 163 us (5.2 TB/s).
// R4: + nontemporal load/store -> 150.6 us (5.64 TB/s).
// R5: single combined per-block zero-check + branch-free 64 KB copy,
//     8 loads in flight per thread (deeper MLP, no per-head branches).

#define NH 25920
#define NS 64
#define ND 64
#define HEADS_PER_BLOCK 4

typedef float f32x4 __attribute__((ext_vector_type(4)));

__device__ __forceinline__ uint32_t rotl32(uint32_t x, int n) {
  return (x << n) | (x >> (32 - n));
}

// JAX threefry2x32 with key = jax.random.key(42) -> (k0,k1) = (0,42).
__device__ __forceinline__ void threefry2x32_0_42(uint32_t x0, uint32_t x1,
                                                  uint32_t& y0, uint32_t& y1) {
  const uint32_t ks0 = 0u;
  const uint32_t ks1 = 42u;
  const uint32_t ks2 = 0u ^ 42u ^ 0x1BD11BDAu;
  x0 += ks0; x1 += ks1;
#define RND(r) { x0 += x1; x1 = rotl32(x1, (r)); x1 ^= x0; }
  RND(13) RND(15) RND(26) RND(6)
  x0 += ks1; x1 += ks2 + 1u;
  RND(17) RND(29) RND(16) RND(24)
  x0 += ks2; x1 += ks0 + 2u;
  RND(13) RND(15) RND(26) RND(6)
  x0 += ks0; x1 += ks1 + 3u;
  RND(17) RND(29) RND(16) RND(24)
  x0 += ks1; x1 += ks2 + 4u;
  RND(13) RND(15) RND(26) RND(6)
  x0 += ks2; x1 += ks0 + 5u;
#undef RND
  y0 = x0; y1 = x1;
}

__global__ void __launch_bounds__(256)
fused_residual_kernel(const f32x4* __restrict__ qt4,
                      const float* __restrict__ biasb,
                      f32x4* __restrict__ out4) {
  const int h0 = blockIdx.x * HEADS_PER_BLOCK;
  // One scalar load per head, one combined uniform branch for the block.
  const float b0 = biasb[h0 + 0];
  const float b1 = biasb[h0 + 1];
  const float b2 = biasb[h0 + 2];
  const float b3 = biasb[h0 + 3];
  const uint32_t nz = __float_as_uint(b0) | __float_as_uint(b1) |
                      __float_as_uint(b2) | __float_as_uint(b3);
  const int base = h0 << 10;  // 1024 float4 per head, 4096 per block

  if (nz == 0u) {
    // Hot path: branch-free 64 KB slab copy, 8 loads in flight per thread.
    const f32x4* __restrict__ src = qt4 + base + threadIdx.x;
    f32x4* __restrict__ dst = out4 + base + threadIdx.x;
#pragma unroll
    for (int g = 0; g < 2; ++g) {
      f32x4 v0 = __builtin_nontemporal_load(src + 0 * 256);
      f32x4 v1 = __builtin_nontemporal_load(src + 1 * 256);
      f32x4 v2 = __builtin_nontemporal_load(src + 2 * 256);
      f32x4 v3 = __builtin_nontemporal_load(src + 3 * 256);
      f32x4 v4 = __builtin_nontemporal_load(src + 4 * 256);
      f32x4 v5 = __builtin_nontemporal_load(src + 5 * 256);
      f32x4 v6 = __builtin_nontemporal_load(src + 6 * 256);
      f32x4 v7 = __builtin_nontemporal_load(src + 7 * 256);
      __builtin_nontemporal_store(v0, dst + 0 * 256);
      __builtin_nontemporal_store(v1, dst + 1 * 256);
      __builtin_nontemporal_store(v2, dst + 2 * 256);
      __builtin_nontemporal_store(v3, dst + 3 * 256);
      __builtin_nontemporal_store(v4, dst + 4 * 256);
      __builtin_nontemporal_store(v5, dst + 5 * 256);
      __builtin_nontemporal_store(v6, dst + 6 * 256);
      __builtin_nontemporal_store(v7, dst + 7 * 256);
      src += 8 * 256;
      dst += 8 * 256;
    }
    return;
  }

  // Robust fallback: exact JAX bernoulli(key(42), keep, (NH*NS,1)) mask.
  const float keep = 0.2021470392102155f;
  const float bs[HEADS_PER_BLOCK] = {b0, b1, b2, b3};
#pragma unroll
  for (int hh = 0; hh < HEADS_PER_BLOCK; ++hh) {
    const float b = bs[hh];
    const int hbase = base + (hh << 10);
#pragma unroll
    for (int j = 0; j < 4; ++j) {
      const int t = (j << 8) + threadIdx.x;   // 0..1023 within slab
      const int idx = hbase + t;
      const uint32_t row = (uint32_t)(((h0 + hh) << 6) + (t >> 4));
      const uint32_t n = (uint32_t)(NH * NS);
      const uint32_t half = n >> 1;
      uint32_t x0, x1, y0, y1;
      const bool hi = (row >= half);
      if (hi) { x0 = row - half; x1 = row; } else { x0 = row; x1 = row + half; }
      threefry2x32_0_42(x0, x1, y0, y1);
      const uint32_t bits = hi ? y1 : y0;
      const float u = __uint_as_float((bits >> 9) | 0x3F800000u) - 1.0f;
      const float add = (u < keep && b != 0.0f) ? (b / keep) : 0.0f;
      f32x4 v = __builtin_nontemporal_load(&qt4[idx]);
      v.x += add; v.y += add; v.z += add; v.w += add;
      __builtin_nontemporal_store(v, &out4[idx]);
    }
  }
}

extern "C" void kernel_launch(void* const* d_in, const int* in_sizes, int n_in,
                              void* d_out, int out_size, void* d_ws, size_t ws_size,
                              hipStream_t stream) {
  const f32x4* qt4 = (const f32x4*)d_in[0];
  // d_in[1] = k (unused), d_in[2] = scaleb (unused)
  const float* biasb = (const float*)d_in[3];
  f32x4* out4 = (f32x4*)d_out;

  const int grid = NH / HEADS_PER_BLOCK;  // 6480 blocks, 4 heads (64 KB) each
  fused_residual_kernel<<<grid, 256, 0, stream>>>(qt4, biasb, out4);
}

// Round 7
// 158.907 us; speedup vs baseline: 1.0355x; 1.0355x over previous
//
#include <hip/hip_runtime.h>
#include <stdint.h>

// Problem constants (fixed by reference setup_inputs):
//   qt:     (H=25920, S=64, D=64) f32
//   k:      (H, 1, D) f32          -- DEAD: softmax over singleton axis == 1
//   scaleb: (H, 1, 1) f32          -- DEAD: same reason
//   biasb:  (H, 1, 1) f32          -- zeros in setup; a5 = mask * biasb/keep
// out = qt + broadcast(a5) ; a5[h,s] = (bernoulli_keep ? 1/keep : 0) * biasb[h]
//
// R0: per-element biasb load + branch -> 175 us (4.85 TB/s).
// R1: serial scan kernel + global flag -> 202 us (regression).
// R2: per-head slab copy, wave-uniform biasb -> 163 us (5.2 TB/s).
// R4: + nontemporal load/store -> 150.6 us (5.64 TB/s).
// R5: 8-deep load/store batches -> 164.5 us (regression: interleaved
//     load/store pairs beat batched bursts).
// R6: split. Hot kernel = branch-free nt copy (m13 pattern, zero biasb
//     reads, exact-division grid). Fixup kernel handles biasb!=0 heads
//     (no-op + ~104 KB read when biasb is all zeros).

#define NH 25920
#define NS 64
#define ND 64

typedef float f32x4 __attribute__((ext_vector_type(4)));

__device__ __forceinline__ uint32_t rotl32(uint32_t x, int n) {
  return (x << n) | (x >> (32 - n));
}

// JAX threefry2x32 with key = jax.random.key(42) -> (k0,k1) = (0,42).
__device__ __forceinline__ void threefry2x32_0_42(uint32_t x0, uint32_t x1,
                                                  uint32_t& y0, uint32_t& y1) {
  const uint32_t ks0 = 0u;
  const uint32_t ks1 = 42u;
  const uint32_t ks2 = 0u ^ 42u ^ 0x1BD11BDAu;
  x0 += ks0; x1 += ks1;
#define RND(r) { x0 += x1; x1 = rotl32(x1, (r)); x1 ^= x0; }
  RND(13) RND(15) RND(26) RND(6)
  x0 += ks1; x1 += ks2 + 1u;
  RND(17) RND(29) RND(16) RND(24)
  x0 += ks2; x1 += ks0 + 2u;
  RND(13) RND(15) RND(26) RND(6)
  x0 += ks0; x1 += ks1 + 3u;
  RND(17) RND(29) RND(16) RND(24)
  x0 += ks1; x1 += ks2 + 4u;
  RND(13) RND(15) RND(26) RND(6)
  x0 += ks2; x1 += ks0 + 5u;
#undef RND
  y0 = x0; y1 = x1;
}

// Kernel 1: pure streaming copy, no biasb dependency, no branches.
// grid 5184 x 256: 1,327,104 threads x exactly 20 float4 each.
__global__ void __launch_bounds__(256)
copy_kernel(const f32x4* __restrict__ src, f32x4* __restrict__ dst,
            int total4) {
  const int stride = gridDim.x * 256;
  int i = blockIdx.x * 256 + threadIdx.x;
  int i2 = i + stride;
  for (; i2 < total4; i = i2 + stride, i2 = i + stride) {
    f32x4 a = __builtin_nontemporal_load(src + i);
    f32x4 b = __builtin_nontemporal_load(src + i2);
    __builtin_nontemporal_store(a, dst + i);
    __builtin_nontemporal_store(b, dst + i2);
  }
  if (i < total4) {
    f32x4 a = __builtin_nontemporal_load(src + i);
    __builtin_nontemporal_store(a, dst + i);
  }
}

// Kernel 2: fixup for biasb != 0 heads. One wave per head; all-zero biasb
// -> every wave early-exits after one broadcast load.
__global__ void __launch_bounds__(256)
fixup_kernel(const float* __restrict__ biasb, f32x4* __restrict__ out4) {
  const int wave = threadIdx.x >> 6;
  const int lane = threadIdx.x & 63;
  const int h = blockIdx.x * 4 + wave;
  const float b = biasb[h];          // same addr per wave -> broadcast
  if (b == 0.0f) return;             // wave-uniform
  // Exact JAX bernoulli(key(42), keep, (NH*NS,1)) for row = h*64 + lane.
  const float keep = 0.2021470392102155f;
  const uint32_t row = (uint32_t)((h << 6) + lane);
  const uint32_t n = (uint32_t)(NH * NS);
  const uint32_t half = n >> 1;
  uint32_t x0, x1, y0, y1;
  const bool hi = (row >= half);
  if (hi) { x0 = row - half; x1 = row; } else { x0 = row; x1 = row + half; }
  threefry2x32_0_42(x0, x1, y0, y1);
  const uint32_t bits = hi ? y1 : y0;
  const float u = __uint_as_float((bits >> 9) | 0x3F800000u) - 1.0f;
  if (u >= keep) return;             // dropped -> a5 row is 0, out already qt
  const float add = b / keep;        // softmax over singleton == 1
  f32x4* p = out4 + ((h << 10) + (lane << 4));  // this row's 16 float4
#pragma unroll
  for (int j = 0; j < 16; ++j) {
    f32x4 v = p[j];
    v.x += add; v.y += add; v.z += add; v.w += add;
    p[j] = v;
  }
}

extern "C" void kernel_launch(void* const* d_in, const int* in_sizes, int n_in,
                              void* d_out, int out_size, void* d_ws, size_t ws_size,
                              hipStream_t stream) {
  const f32x4* qt4 = (const f32x4*)d_in[0];
  // d_in[1] = k (unused), d_in[2] = scaleb (unused)
  const float* biasb = (const float*)d_in[3];
  f32x4* out4 = (f32x4*)d_out;

  const int total4 = (NH * NS * ND) / 4;  // 26,542,080 = 5184*256*20 exactly
  copy_kernel<<<5184, 256, 0, stream>>>(qt4, out4, total4);
  fixup_kernel<<<NH / 4, 256, 0, stream>>>(biasb, out4);
}